// Round 5
// baseline (279.006 us; speedup 1.0000x reference)
//
#include <hip/hip_runtime.h>

// SSIM (32,3,512,512) fp32, crop 4, 11x11 Gaussian sigma=1.5, per-batch mean.
//
// V6: true 64-VGPR fit (no spill) to unlock 5 blocks/CU.
//  V5 hit "64 VGPR" only via ~7 dwords/thread scratch spill (WRITE_SIZE 112MB).
//  Pressure cuts: Stage A tasks = 2 rows x 2 COLS (16 accs, was 32);
//  symmetric 11-tap -> 6 weight regs; Stage B folds SSIM incrementally
//  (peak ~56 regs). Work, bytes, and LDS layout unchanged vs V5.
//  Fields: r, d, s2=r^2+d^2, p2=(r+d)^2;  2*cov = conv(p2)-conv(s2)-2*mr*md.
//  Tile 64x26 (19*26=494 exact). LDS 31.7KB -> 5 blocks/CU at <=64 VGPR.

#define IMG   512
#define OUTD  494
#define CB    4
#define TW    64
#define TH    26
#define VSW   76           // 38 float2 groups; row = 304 B
#define C1F   6.5025f
#define C2F   58.5225f
#define NPIX  732108.0f    // 3*494*494
#define XBLK  8
#define YBLK  19           // 19 * 26 = 494 exact
#define SLOTS 456          // XBLK*YBLK*3 partials per batch

// tap weight k in 0..10, from 6 unique symmetric values (compile-time k)
#define GW(k) g[(k) <= 5 ? (k) : 10 - (k)]

__global__ __launch_bounds__(256, 4) void ssim_main(
        const float* __restrict__ raw, const float* __restrict__ dst,
        float* __restrict__ partial) {
    __shared__ float vs[4][TH][VSW];   // 31616 B -> LDS caps at 5 blocks/CU
    __shared__ float red[4];

    const int tid = threadIdx.x;
    const int bc  = blockIdx.z;
    const int b   = bc / 3;
    const int c3  = bc - b * 3;
    const int ty0 = blockIdx.y * TH;
    const int tx0 = blockIdx.x * TW;

    // 6 unique Gaussian weights (11-tap symmetric), matches jnp reference:
    // g[i] = exp(-(i-5)^2/4.5) / sum_{k=0..10} exp(-(k-5)^2/4.5)
    float g[6];
    {
        float t[6];
        #pragma unroll
        for (int k = 0; k < 6; ++k) {
            const float x = (float)(k - 5);
            t[k] = expf(-x * x * (1.0f / 4.5f));
        }
        const float s = 2.f * (t[0] + t[1] + t[2] + t[3] + t[4]) + t[5];
        const float inv = 1.0f / s;
        #pragma unroll
        for (int k = 0; k < 6; ++k) g[k] = t[k] * inv;
    }

    const float* rb = raw + (size_t)bc * (IMG * IMG);
    const float* db = dst + (size_t)bc * (IMG * IMG);

    // ---- Stage A: vertical conv. 494 tasks = 13 row-pairs x 38 col-pairs,
    //      2 rounds over 256 threads. 16 accumulators/task (fits 64 VGPR). ----
    #pragma unroll 1
    for (int t = tid; t < 494; t += 256) {
        const int rp = t / 38;
        const int xg = t - rp * 38;
        int col0 = CB + tx0 + xg * 2;
        if (col0 > IMG - 2) col0 = IMG - 2;    // edge blocks: garbage cols unused
        const int row0 = CB + ty0 + rp * 2;    // max 496; +11 = 507 < 512

        float a0[4][2] = {{0.f}};   // moments for vs-row rp*2
        float a1[4][2] = {{0.f}};   // moments for vs-row rp*2+1
        #pragma unroll
        for (int k = 0; k < 12; ++k) {
            const int r = row0 + k;
            const float2 va = *(const float2*)(rb + (size_t)r * IMG + col0);
            const float2 vc = *(const float2*)(db + (size_t)r * IMG + col0);
            const float R[2] = {va.x, va.y};
            const float D[2] = {vc.x, vc.y};
            float s2[2], p2[2];
            #pragma unroll
            for (int c = 0; c < 2; ++c) {
                const float u = R[c] + D[c];
                s2[c] = fmaf(R[c], R[c], D[c] * D[c]);   // r^2 + d^2
                p2[c] = u * u;                           // (r+d)^2
            }
            if (k < 11) {
                const float w = GW(k);
                #pragma unroll
                for (int c = 0; c < 2; ++c) {
                    a0[0][c] = fmaf(w, R[c],  a0[0][c]);
                    a0[1][c] = fmaf(w, D[c],  a0[1][c]);
                    a0[2][c] = fmaf(w, s2[c], a0[2][c]);
                    a0[3][c] = fmaf(w, p2[c], a0[3][c]);
                }
            }
            if (k >= 1) {
                const float w = GW(k - 1);
                #pragma unroll
                for (int c = 0; c < 2; ++c) {
                    a1[0][c] = fmaf(w, R[c],  a1[0][c]);
                    a1[1][c] = fmaf(w, D[c],  a1[1][c]);
                    a1[2][c] = fmaf(w, s2[c], a1[2][c]);
                    a1[3][c] = fmaf(w, p2[c], a1[3][c]);
                }
            }
        }
        #pragma unroll
        for (int f = 0; f < 4; ++f) {
            *(float2*)&vs[f][rp * 2 + 0][xg * 2] = make_float2(a0[f][0], a0[f][1]);
            *(float2*)&vs[f][rp * 2 + 1][xg * 2] = make_float2(a1[f][0], a1[f][1]);
        }
    }
    __syncthreads();

    // ---- Stage B: horizontal conv + SSIM. Thread = 8 cols x 1 row. ----
    // row = tid&31, xg = tid>>5: 8-lane phase groups span 8 rows ->
    // banks 12*row+c cover all 32 -> conflict-free ds_read_b128.
    const int row = tid & 31;
    const int xg  = tid >> 5;
    const int ox0 = tx0 + xg * 8;

    // symmetric 11-tap over an 18-float window, 8 outputs
    #define HCONV(f, o)                                                      \
    {                                                                        \
        const float4* vp = (const float4*)&vs[f][row][xg * 8];               \
        const float4 A = vp[0], B = vp[1], Cq = vp[2], Dq = vp[3];           \
        const float2 E2 = *(const float2*)&vs[f][row][xg * 8 + 16];          \
        const float w_[18] = {A.x, A.y, A.z, A.w,  B.x, B.y, B.z, B.w,       \
                              Cq.x, Cq.y, Cq.z, Cq.w, Dq.x, Dq.y, Dq.z, Dq.w,\
                              E2.x, E2.y};                                   \
        _Pragma("unroll")                                                    \
        for (int c = 0; c < 8; ++c) {                                        \
            float t5 = g[5] * w_[c + 5];                                     \
            _Pragma("unroll")                                                \
            for (int j = 0; j < 5; ++j)                                      \
                t5 = fmaf(g[j], w_[c + j] + w_[c + 10 - j], t5);             \
            o[c] = t5;                                                       \
        }                                                                    \
    }

    float ssum = 0.f;
    if (row < TH) {                     // oy = ty0+row < 494 always (19*26=494)
        float m0[8], m1[8];
        HCONV(0, m0);
        HCONV(1, m1);
        float q1[8], q2[8];             // mr^2+md^2, mr*md (scaled)
        #pragma unroll
        for (int c = 0; c < 8; ++c) {
            const float a = m0[c] * 255.0f;
            const float d = m1[c] * 255.0f;
            q1[c] = fmaf(a, a, d * d);
            q2[c] = a * d;
        }
        float S2[8];                    // E[r^2]+E[d^2] (scaled below)
        HCONV(2, S2);
        float den[8];
        #pragma unroll
        for (int c = 0; c < 8; ++c) {
            S2[c] *= 65025.0f;
            den[c] = (q1[c] + C1F) * ((S2[c] - q1[c]) + C2F);
        }
        float P2[8];                    // E[(r+d)^2]
        HCONV(3, P2);
        #pragma unroll
        for (int c = 0; c < 8; ++c) {
            if (ox0 + c < OUTD) {
                const float P   = P2[c] * 65025.0f;
                const float num = fmaf(2.0f, q2[c], C1F) *
                                  ((P - S2[c]) - 2.0f * q2[c] + C2F);
                // den >= C1*C2 ~ 380: well-conditioned; v_rcp_f32 ~1ulp
                ssum = fmaf(num, __builtin_amdgcn_rcpf(den[c]), ssum);
            }
        }
    }

    // block reduction -> unique partial slot (no atomics)
    #pragma unroll
    for (int off = 32; off > 0; off >>= 1)
        ssum += __shfl_down(ssum, off, 64);
    const int lane = tid & 63, wv = tid >> 6;
    if (lane == 0) red[wv] = ssum;
    __syncthreads();
    if (tid == 0) {
        const float t = red[0] + red[1] + red[2] + red[3];
        partial[(size_t)b * SLOTS + (blockIdx.y * gridDim.x + blockIdx.x) * 3 + c3] = t;
    }
}

__global__ __launch_bounds__(128) void ssim_final(
        const float* __restrict__ partial, float* __restrict__ out) {
    __shared__ float red[2];
    const int b = blockIdx.x, tid = threadIdx.x;
    float s = 0.f;
    for (int i = tid; i < SLOTS; i += 128) s += partial[(size_t)b * SLOTS + i];
    #pragma unroll
    for (int off = 32; off > 0; off >>= 1) s += __shfl_down(s, off, 64);
    if ((tid & 63) == 0) red[tid >> 6] = s;
    __syncthreads();
    if (tid == 0) out[b] = (red[0] + red[1]) * (1.0f / NPIX);
}

extern "C" void kernel_launch(void* const* d_in, const int* in_sizes, int n_in,
                              void* d_out, int out_size, void* d_ws, size_t ws_size,
                              hipStream_t stream) {
    const float* raw = (const float*)d_in[0];
    const float* dst = (const float*)d_in[1];
    float* out     = (float*)d_out;
    float* partial = (float*)d_ws;   // 32*456 fp32, fully overwritten each call

    dim3 grid(XBLK, YBLK, 96);       // 8 x 19 x (32 batches * 3 channels)
    ssim_main<<<grid, 256, 0, stream>>>(raw, dst, partial);
    ssim_final<<<32, 128, 0, stream>>>(partial, out);
}

// Round 6
// 238.198 us; speedup vs baseline: 1.1713x; 1.1713x over previous
//
#include <hip/hip_runtime.h>

// SSIM (32,3,512,512) fp32, crop 4, 11x11 Gaussian sigma=1.5, per-batch mean.
//
// V7: column-streaming Stage A (1 col x 9 outputs per task).
//  vs V6: loads/cell 6 -> 2.1 per image (19 rows serve 9 outputs), square-prep
//  redundancy 6x -> 2.1x (-21% Stage-A VALU), ds_write_b32 lane-consecutive
//  (2/bank = free; V6's float2 write pattern doubled conflicts to 2.6e7).
//  228 tasks = 76 cols x 3 row-groups (starts 0,9,17: overlap keeps writes
//  in-bounds, no guards). Single round, balanced. accs 4x9=36 -> fits 64 VGPR.
//  Stage B: V6's verified conflict-free map (row=tid&31 -> banks 12*row+c).
//  Fields: r, d, s2=r^2+d^2, p2=(r+d)^2;  2*cov = conv(p2)-conv(s2)-2*mr*md.

#define IMG   512
#define OUTD  494
#define CB    4
#define TW    64
#define TH    26
#define VSW   76           // row = 304 B (16B-aligned for b128 Stage-B reads)
#define C1F   6.5025f
#define C2F   58.5225f
#define NPIX  732108.0f    // 3*494*494
#define XBLK  8
#define YBLK  19           // 19 * 26 = 494 exact
#define SLOTS 456          // XBLK*YBLK*3 partials per batch
#define NV    9            // outputs per Stage-A task

// tap weight k in 0..10, from 6 unique symmetric values (compile-time k)
#define GW(k) g[(k) <= 5 ? (k) : 10 - (k)]

__global__ __launch_bounds__(256, 4) void ssim_main(
        const float* __restrict__ raw, const float* __restrict__ dst,
        float* __restrict__ partial) {
    __shared__ float vs[4][TH][VSW];   // 31616 B -> LDS caps at 5 blocks/CU
    __shared__ float red[4];

    const int tid = threadIdx.x;
    const int bc  = blockIdx.z;
    const int b   = bc / 3;
    const int c3  = bc - b * 3;
    const int ty0 = blockIdx.y * TH;
    const int tx0 = blockIdx.x * TW;

    // 6 unique Gaussian weights (11-tap symmetric), matches jnp reference:
    // g[i] = exp(-(i-5)^2/4.5) / sum_{k=0..10} exp(-(k-5)^2/4.5)
    float g[6];
    {
        float t[6];
        #pragma unroll
        for (int k = 0; k < 6; ++k) {
            const float x = (float)(k - 5);
            t[k] = expf(-x * x * (1.0f / 4.5f));
        }
        const float s = 2.f * (t[0] + t[1] + t[2] + t[3] + t[4]) + t[5];
        const float inv = 1.0f / s;
        #pragma unroll
        for (int k = 0; k < 6; ++k) g[k] = t[k] * inv;
    }

    const float* rb = raw + (size_t)bc * (IMG * IMG);
    const float* db = dst + (size_t)bc * (IMG * IMG);

    // ---- Stage A: vertical conv, column-streaming.
    //      228 tasks = 76 cols x 3 row-groups (starts 0,9,17). ----
    if (tid < 228) {
        const int c  = tid % 76;
        const int rg = tid / 76;
        const int start = (rg == 2) ? 17 : rg * 9;   // rows start..start+8 < 26
        int gcol = CB + tx0 + c;
        if (gcol > IMG - 1) gcol = IMG - 1;   // edge blocks: cols >73 unused
        const int row0 = CB + ty0 + start;    // max 468+4+17=489; +18=507 < 512

        const float* rp_ = rb + (size_t)row0 * IMG + gcol;
        const float* dp_ = db + (size_t)row0 * IMG + gcol;

        float acc[4][NV];
        #pragma unroll
        for (int f = 0; f < 4; ++f)
            #pragma unroll
            for (int o = 0; o < NV; ++o) acc[f][o] = 0.f;

        #pragma unroll
        for (int k = 0; k < NV + 10; ++k) {
            const float R = rp_[(size_t)k * IMG];
            const float D = dp_[(size_t)k * IMG];
            const float u  = R + D;
            const float s2 = fmaf(R, R, D * D);   // r^2 + d^2
            const float p2 = u * u;               // (r+d)^2
            #pragma unroll
            for (int o = 0; o < NV; ++o) {
                const int kk = k - o;             // compile-time
                if (kk >= 0 && kk <= 10) {
                    const float w = GW(kk);
                    acc[0][o] = fmaf(w, R,  acc[0][o]);
                    acc[1][o] = fmaf(w, D,  acc[1][o]);
                    acc[2][o] = fmaf(w, s2, acc[2][o]);
                    acc[3][o] = fmaf(w, p2, acc[3][o]);
                }
            }
        }
        // lane-consecutive b32 writes: 2 lanes/bank = conflict-free
        #pragma unroll
        for (int f = 0; f < 4; ++f)
            #pragma unroll
            for (int o = 0; o < NV; ++o)
                vs[f][start + o][c] = acc[f][o];
    }
    __syncthreads();

    // ---- Stage B: horizontal conv + SSIM. Thread = 8 cols x 1 row. ----
    // row = tid&31, xg = tid>>5: 8-lane phase groups span 8 rows ->
    // banks 12*row+c cover all 32 -> conflict-free ds_read_b128.
    const int row = tid & 31;
    const int xg  = tid >> 5;
    const int ox0 = tx0 + xg * 8;

    // symmetric 11-tap over an 18-float window, 8 outputs
    #define HCONV(f, o)                                                      \
    {                                                                        \
        const float4* vp = (const float4*)&vs[f][row][xg * 8];               \
        const float4 A = vp[0], B = vp[1], Cq = vp[2], Dq = vp[3];           \
        const float2 E2 = *(const float2*)&vs[f][row][xg * 8 + 16];          \
        const float w_[18] = {A.x, A.y, A.z, A.w,  B.x, B.y, B.z, B.w,       \
                              Cq.x, Cq.y, Cq.z, Cq.w, Dq.x, Dq.y, Dq.z, Dq.w,\
                              E2.x, E2.y};                                   \
        _Pragma("unroll")                                                    \
        for (int c = 0; c < 8; ++c) {                                        \
            float t5 = g[5] * w_[c + 5];                                     \
            _Pragma("unroll")                                                \
            for (int j = 0; j < 5; ++j)                                      \
                t5 = fmaf(g[j], w_[c + j] + w_[c + 10 - j], t5);             \
            o[c] = t5;                                                       \
        }                                                                    \
    }

    float ssum = 0.f;
    if (row < TH) {                     // oy = ty0+row < 494 always (19*26=494)
        float m0[8], m1[8];
        HCONV(0, m0);
        HCONV(1, m1);
        float q1[8], q2[8];             // mr^2+md^2, mr*md (scaled)
        #pragma unroll
        for (int c = 0; c < 8; ++c) {
            const float a = m0[c] * 255.0f;
            const float d = m1[c] * 255.0f;
            q1[c] = fmaf(a, a, d * d);
            q2[c] = a * d;
        }
        float S2[8];                    // E[r^2]+E[d^2] (scaled below)
        HCONV(2, S2);
        float den[8];
        #pragma unroll
        for (int c = 0; c < 8; ++c) {
            S2[c] *= 65025.0f;
            den[c] = (q1[c] + C1F) * ((S2[c] - q1[c]) + C2F);
        }
        float P2[8];                    // E[(r+d)^2]
        HCONV(3, P2);
        #pragma unroll
        for (int c = 0; c < 8; ++c) {
            if (ox0 + c < OUTD) {
                const float P   = P2[c] * 65025.0f;
                const float num = fmaf(2.0f, q2[c], C1F) *
                                  ((P - S2[c]) - 2.0f * q2[c] + C2F);
                // den >= C1*C2 ~ 380: well-conditioned; v_rcp_f32 ~1ulp
                ssum = fmaf(num, __builtin_amdgcn_rcpf(den[c]), ssum);
            }
        }
    }

    // block reduction -> unique partial slot (no atomics)
    #pragma unroll
    for (int off = 32; off > 0; off >>= 1)
        ssum += __shfl_down(ssum, off, 64);
    const int lane = tid & 63, wv = tid >> 6;
    if (lane == 0) red[wv] = ssum;
    __syncthreads();
    if (tid == 0) {
        const float t = red[0] + red[1] + red[2] + red[3];
        partial[(size_t)b * SLOTS + (blockIdx.y * gridDim.x + blockIdx.x) * 3 + c3] = t;
    }
}

__global__ __launch_bounds__(128) void ssim_final(
        const float* __restrict__ partial, float* __restrict__ out) {
    __shared__ float red[2];
    const int b = blockIdx.x, tid = threadIdx.x;
    float s = 0.f;
    for (int i = tid; i < SLOTS; i += 128) s += partial[(size_t)b * SLOTS + i];
    #pragma unroll
    for (int off = 32; off > 0; off >>= 1) s += __shfl_down(s, off, 64);
    if ((tid & 63) == 0) red[tid >> 6] = s;
    __syncthreads();
    if (tid == 0) out[b] = (red[0] + red[1]) * (1.0f / NPIX);
}

extern "C" void kernel_launch(void* const* d_in, const int* in_sizes, int n_in,
                              void* d_out, int out_size, void* d_ws, size_t ws_size,
                              hipStream_t stream) {
    const float* raw = (const float*)d_in[0];
    const float* dst = (const float*)d_in[1];
    float* out     = (float*)d_out;
    float* partial = (float*)d_ws;   // 32*456 fp32, fully overwritten each call

    dim3 grid(XBLK, YBLK, 96);       // 8 x 19 x (32 batches * 3 channels)
    ssim_main<<<grid, 256, 0, stream>>>(raw, dst, partial);
    ssim_final<<<32, 128, 0, stream>>>(partial, out);
}